// Round 5
// baseline (909.976 us; speedup 1.0000x reference)
//
#include <hip/hip_runtime.h>
#include <hip/hip_bf16.h>

#define N_NODES 200000
#define N_EDGES 3200000
#define FEATS   256
#define NC      32

#define NBPB    256                      // nodes per bucket (dst >> 8)
#define BUCKETS 782                      // ceil(200000 / 256)

typedef __attribute__((ext_vector_type(8))) short bf16x8;
typedef __attribute__((ext_vector_type(4))) float f32x4;

__device__ __forceinline__ float atomAddF(float* p, float v) {
    return unsafeAtomicAdd(p, v);
}
__device__ __forceinline__ short f2bf(float f) {
    return (short)__bfloat16_as_ushort(__float2bfloat16(f));
}

// ---------------------------------------------------------------------------
// Kernel 1: h = x @ W^T + bias via bf16 MFMA. W in registers, x streamed.
// Fused: S1[c] += (u[n]/N)*h[n,c], S2 += (...)^2   (verified round 3)
// ---------------------------------------------------------------------------
__global__ __launch_bounds__(256, 3) void k_linear(
    const float* __restrict__ x, const float* __restrict__ Wmat,
    const float* __restrict__ bias, const float* __restrict__ u_sum,
    float* __restrict__ h, float* __restrict__ S1, float* __restrict__ S2)
{
    __shared__ float lds_s1[4][32];
    __shared__ float lds_s2[4];

    const int lane = threadIdx.x & 63;
    const int wv   = threadIdx.x >> 6;
    const int lr   = lane & 15;
    const int kc   = lane >> 4;

    bf16x8 bfr[8][2];
    #pragma unroll
    for (int ct = 0; ct < 2; ++ct) {
        const float* wp = Wmat + (size_t)(ct * 16 + lr) * FEATS + kc * 8;
        #pragma unroll
        for (int kt = 0; kt < 8; ++kt) {
            f32x4 v0 = *(const f32x4*)(wp + kt * 32);
            f32x4 v1 = *(const f32x4*)(wp + kt * 32 + 4);
            bf16x8 b;
            b[0]=f2bf(v0.x); b[1]=f2bf(v0.y); b[2]=f2bf(v0.z); b[3]=f2bf(v0.w);
            b[4]=f2bf(v1.x); b[5]=f2bf(v1.y); b[6]=f2bf(v1.z); b[7]=f2bf(v1.w);
            bfr[kt][ct] = b;
        }
    }

    const float bias0 = bias[lr], bias1 = bias[16 + lr];
    const float invn = 1.0f / (float)N_NODES;
    float s1_0 = 0.f, s1_1 = 0.f, s2 = 0.f;

    const int ntiles = N_NODES / 16;
    for (int t = blockIdx.x * 4 + wv; t < ntiles; t += gridDim.x * 4) {
        const int base = t * 16;
        const float* xp = x + (size_t)(base + lr) * FEATS + kc * 8;
        f32x4 acc0 = {bias0, bias0, bias0, bias0};
        f32x4 acc1 = {bias1, bias1, bias1, bias1};
        #pragma unroll
        for (int kt = 0; kt < 8; ++kt) {
            f32x4 v0 = *(const f32x4*)(xp + kt * 32);
            f32x4 v1 = *(const f32x4*)(xp + kt * 32 + 4);
            bf16x8 a;
            a[0]=f2bf(v0.x); a[1]=f2bf(v0.y); a[2]=f2bf(v0.z); a[3]=f2bf(v0.w);
            a[4]=f2bf(v1.x); a[5]=f2bf(v1.y); a[6]=f2bf(v1.z); a[7]=f2bf(v1.w);
            acc0 = __builtin_amdgcn_mfma_f32_16x16x32_bf16(a, bfr[kt][0], acc0, 0, 0, 0);
            acc1 = __builtin_amdgcn_mfma_f32_16x16x32_bf16(a, bfr[kt][1], acc1, 0, 0, 0);
        }
        #pragma unroll
        for (int i = 0; i < 4; ++i) {
            const int row = base + kc * 4 + i;
            h[(size_t)row * NC + lr]      = acc0[i];
            h[(size_t)row * NC + 16 + lr] = acc1[i];
            const float um = u_sum[row] * invn;
            float a0 = um * acc0[i], a1 = um * acc1[i];
            s1_0 += a0; s1_1 += a1;
            s2 += a0 * a0 + a1 * a1;
        }
    }

    s1_0 += __shfl_xor(s1_0, 16); s1_0 += __shfl_xor(s1_0, 32);
    s1_1 += __shfl_xor(s1_1, 16); s1_1 += __shfl_xor(s1_1, 32);
    #pragma unroll
    for (int off = 1; off < 64; off <<= 1) s2 += __shfl_xor(s2, off);
    if (lane < 16) { lds_s1[wv][lr] = s1_0; lds_s1[wv][16 + lr] = s1_1; }
    if (lane == 0) lds_s2[wv] = s2;
    __syncthreads();
    if (threadIdx.x < 32) {
        float t4 = lds_s1[0][threadIdx.x] + lds_s1[1][threadIdx.x]
                 + lds_s1[2][threadIdx.x] + lds_s1[3][threadIdx.x];
        atomAddF(&S1[threadIdx.x], t4);
    }
    if (threadIdx.x == 32)
        atomAddF(S2, lds_s2[0] + lds_s2[1] + lds_s2[2] + lds_s2[3]);
}

// ---------------------------------------------------------------------------
// Bucketing: count -> scan -> multisplit scatter. 8192-edge tiles.
// ---------------------------------------------------------------------------
__global__ __launch_bounds__(512) void k_count(
    const int* __restrict__ dst, int* __restrict__ cnt)
{
    __shared__ int hist[BUCKETS];
    for (int i = threadIdx.x; i < BUCKETS; i += 512) hist[i] = 0;
    __syncthreads();
    const int tile = blockIdx.x * 8192;
    #pragma unroll
    for (int i = 0; i < 16; ++i) {
        int e = tile + i * 512 + threadIdx.x;
        if (e < N_EDGES) atomicAdd(&hist[dst[e] >> 8], 1);
    }
    __syncthreads();
    for (int i = threadIdx.x; i < BUCKETS; i += 512)
        if (hist[i]) atomicAdd(&cnt[i], hist[i]);
}

__global__ __launch_bounds__(1024) void k_bscan(
    const int* __restrict__ cnt, int* __restrict__ base, int* __restrict__ pos)
{
    __shared__ int sm[1024];
    int v = (threadIdx.x < BUCKETS) ? cnt[threadIdx.x] : 0;
    sm[threadIdx.x] = v;
    __syncthreads();
    for (int off = 1; off < 1024; off <<= 1) {
        int t = (threadIdx.x >= off) ? sm[threadIdx.x - off] : 0;
        __syncthreads();
        sm[threadIdx.x] += t;
        __syncthreads();
    }
    if (threadIdx.x < BUCKETS) {
        int b = sm[threadIdx.x] - v;
        base[threadIdx.x] = b;
        pos[threadIdx.x]  = b;
    }
}

// payload: x = src | (dst&255)<<18  (src < 2^18), y = w bits
__global__ __launch_bounds__(512) void k_bucket(
    const int* __restrict__ src, const float* __restrict__ w,
    const int* __restrict__ dst, int* __restrict__ pos,
    int2* __restrict__ bucketed)
{
    __shared__ int hist[BUCKETS];
    __shared__ int cursor[BUCKETS];
    for (int i = threadIdx.x; i < BUCKETS; i += 512) hist[i] = 0;
    __syncthreads();

    const int tile = blockIdx.x * 8192;
    int bb[16], dd[16];
    #pragma unroll
    for (int i = 0; i < 16; ++i) {
        int e = tile + i * 512 + threadIdx.x;
        if (e < N_EDGES) {
            dd[i] = dst[e];
            bb[i] = dd[i] >> 8;
            atomicAdd(&hist[bb[i]], 1);
        } else bb[i] = -1;
    }
    __syncthreads();
    for (int i = threadIdx.x; i < BUCKETS; i += 512) {
        int hc = hist[i];
        cursor[i] = hc ? atomicAdd(&pos[i], hc) : 0;
    }
    __syncthreads();
    #pragma unroll
    for (int i = 0; i < 16; ++i) {
        if (bb[i] >= 0) {
            int e = tile + i * 512 + threadIdx.x;
            int p = atomicAdd(&cursor[bb[i]], 1);
            int2 v;
            v.x = src[e] | ((dd[i] & (NBPB - 1)) << 18);
            v.y = __float_as_int(w[e]);
            bucketed[p] = v;
        }
    }
}

// ---------------------------------------------------------------------------
// Per-bucket reduce: y-chunk (32 KB) in LDS. Edge tiles staged in LDS
// (coalesced), 8-deep h-load pipeline per 32-lane group, ds_add_f32
// accumulate, one coalesced y write, colsum fused. 782 blocks, 4 blocks/CU.
// ---------------------------------------------------------------------------
__global__ __launch_bounds__(512, 4) void k_breduce(
    const int2* __restrict__ bucketed, const int* __restrict__ base,
    const int* __restrict__ cnt, const float* __restrict__ h,
    float* __restrict__ y, float* __restrict__ colsum)
{
    __shared__ float ych[NBPB * NC];     // 32 KB
    __shared__ int2  eTile[512];         // 4 KB
    __shared__ float red[512];           // 2 KB
    const int c = threadIdx.x & 31;
    const int g = threadIdx.x >> 5;      // 0..15
    const int b = blockIdx.x;
    float scol = 0.f;

    for (int i = threadIdx.x; i < NBPB * NC; i += 512) ych[i] = 0.f;

    const int beg = base[b], n = cnt[b];
    for (int t0 = 0; t0 < n; t0 += 512) {
        __syncthreads();                 // eTile reuse safe; covers ych init
        const int idx = t0 + threadIdx.x;
        int2 v;
        if (idx < n) v = bucketed[beg + idx];
        else { v.x = 0; v.y = 0; }       // sentinel: w=0 -> adds 0 to ych[0..]
        eTile[threadIdx.x] = v;
        __syncthreads();

        const int2* ep = &eTile[g * 32];
        #pragma unroll
        for (int u0 = 0; u0 < 32; u0 += 8) {
            float vv[8]; int ln[8];
            #pragma unroll
            for (int k = 0; k < 8; ++k) {
                int2 p = ep[u0 + k];     // LDS broadcast (free)
                ln[k] = (int)((unsigned)p.x >> 18);
                vv[k] = h[(size_t)(p.x & 0x3FFFF) * NC + c] * __int_as_float(p.y);
            }
            #pragma unroll
            for (int k = 0; k < 8; ++k)
                atomicAdd(&ych[ln[k] * NC + c], vv[k]);
        }
    }
    __syncthreads();

    const int node0 = b * NBPB;
    const int nn = (N_NODES - node0 < NBPB) ? (N_NODES - node0) : NBPB;
    for (int i = threadIdx.x; i < nn * NC; i += 512) {  // i&31 const per thread
        float v2 = ych[i];
        y[(size_t)node0 * NC + i] = v2;
        scol += v2;
    }

    red[threadIdx.x] = scol;
    __syncthreads();
    if (threadIdx.x < 32) {
        float t = 0.f;
        #pragma unroll
        for (int jj = 0; jj < 16; ++jj) t += red[threadIdx.x + 32 * jj];
        atomAddF(&colsum[threadIdx.x], t);
    }
}

// ---------------------------------------------------------------------------
// Fallback path (small workspace)
// ---------------------------------------------------------------------------
__global__ __launch_bounds__(256) void k_scatter_atomic(
    const float* __restrict__ h, const float* __restrict__ w,
    const int* __restrict__ src, const int* __restrict__ dst,
    float* __restrict__ y)
{
    const long long total  = (long long)N_EDGES * NC;
    const long long stride = (long long)gridDim.x * 256;
    for (long long i = (long long)blockIdx.x * 256 + threadIdx.x;
         i < total; i += stride) {
        const int e = (int)(i >> 5);
        const int c = (int)(i & 31);
        atomAddF(&y[(size_t)dst[e] * NC + c], h[(size_t)src[e] * NC + c] * w[e]);
    }
}

__global__ __launch_bounds__(256) void k_colsum(
    const float* __restrict__ y, float* __restrict__ colsum)
{
    __shared__ float red[256];
    const long long total  = (long long)N_NODES * NC;
    const long long stride = (long long)gridDim.x * 256;
    float s = 0.f;
    for (long long i = (long long)blockIdx.x * 256 + threadIdx.x;
         i < total; i += stride)
        s += y[i];
    red[threadIdx.x] = s;
    __syncthreads();
    if (threadIdx.x < 32) {
        float t = 0.f;
        #pragma unroll
        for (int j = 0; j < 8; ++j) t += red[threadIdx.x + 32 * j];
        atomAddF(&colsum[threadIdx.x], t);
    }
}

// ---------------------------------------------------------------------------
// loss; acc: [0..31] colsum_y, [32..63] S1, [64] S2
// ---------------------------------------------------------------------------
__global__ void k_final(const float* __restrict__ acc, float* __restrict__ loss_out)
{
    double cross = 0.0, msq = 0.0;
    for (int c = 0; c < NC; ++c) {
        double m = (double)acc[c] / (double)N_NODES;
        cross += m * (double)acc[32 + c];
        msq   += m * m;
    }
    double loss = ((double)acc[64] - 2.0 * cross + (double)N_NODES * msq)
                  / ((double)N_NODES * (double)NC);
    *loss_out = (float)loss;
}

extern "C" void kernel_launch(void* const* d_in, const int* in_sizes, int n_in,
                              void* d_out, int out_size, void* d_ws, size_t ws_size,
                              hipStream_t stream)
{
    const float* x   = (const float*)d_in[0];
    const float* w   = (const float*)d_in[1];
    const float* u   = (const float*)d_in[2];
    const float* Wm  = (const float*)d_in[3];
    const float* Wb  = (const float*)d_in[4];
    const int*   src = (const int*)d_in[5];
    const int*   dst = (const int*)d_in[6];

    float* out = (float*)d_out;                  // y [N*32] then loss [1]

    uint8_t* w8 = (uint8_t*)d_ws;
    float* acc  = (float*)w8;                    // 256 floats
    int*   cnt  = (int*)(w8 + 1024);             // BUCKETS (padded 1024)
    int*   base = cnt + 1024;
    int*   pos  = base + 1024;
    float* h    = (float*)(pos + 1024);          // 25.6 MB
    int2*  bucketed = (int2*)(h + (size_t)N_NODES * NC);  // 25.6 MB

    const size_t need = 1024 + 3 * 1024 * 4
                      + (size_t)N_NODES * NC * 4 + (size_t)N_EDGES * 8;

    hipMemsetAsync(acc, 0, 256 * sizeof(float), stream);

    const int NBK = (N_EDGES + 8191) / 8192;     // 391

    if (ws_size >= need) {
        hipMemsetAsync(cnt, 0, BUCKETS * sizeof(int), stream);

        k_linear <<<1024, 256, 0, stream>>>(x, Wm, Wb, u, h, acc + 32, acc + 64);
        k_count  <<<NBK, 512, 0, stream>>>(dst, cnt);
        k_bscan  <<<1, 1024, 0, stream>>>(cnt, base, pos);
        k_bucket <<<NBK, 512, 0, stream>>>(src, w, dst, pos, bucketed);
        k_breduce<<<BUCKETS, 512, 0, stream>>>(bucketed, base, cnt, h, out, acc);
    } else {
        float* h2 = (float*)w8 + 256;
        hipMemsetAsync(d_out, 0, (size_t)out_size * sizeof(float), stream);
        k_linear        <<<1024, 256, 0, stream>>>(x, Wm, Wb, u, h2, acc + 32, acc + 64);
        k_scatter_atomic<<<8192, 256, 0, stream>>>(h2, w, src, dst, out);
        k_colsum        <<<2048, 256, 0, stream>>>(out, acc);
    }

    k_final<<<1, 1, 0, stream>>>(acc, out + (size_t)N_NODES * NC);
}

// Round 6
// 824.756 us; speedup vs baseline: 1.1033x; 1.1033x over previous
//
#include <hip/hip_runtime.h>
#include <hip/hip_bf16.h>

#define N_NODES 200000
#define N_EDGES 3200000
#define FEATS   256
#define NC      32

#define NBPB    256                      // nodes per bucket (dst >> 8)
#define BUCKETS 782                      // ceil(200000 / 256)
#define YSTRIDE 33                       // padded LDS row stride (bank spread)

typedef __attribute__((ext_vector_type(8))) short bf16x8;
typedef __attribute__((ext_vector_type(4))) float f32x4;

__device__ __forceinline__ float atomAddF(float* p, float v) {
    return unsafeAtomicAdd(p, v);
}
__device__ __forceinline__ short f2bf(float f) {
    return (short)__bfloat16_as_ushort(__float2bfloat16(f));
}

// ---------------------------------------------------------------------------
// Kernel 1: h = x @ W^T + bias via bf16 MFMA. W in registers, x streamed.
// Fused: S1[c] += (u[n]/N)*h[n,c], S2 += (...)^2   (verified round 3)
// ---------------------------------------------------------------------------
__global__ __launch_bounds__(256, 3) void k_linear(
    const float* __restrict__ x, const float* __restrict__ Wmat,
    const float* __restrict__ bias, const float* __restrict__ u_sum,
    float* __restrict__ h, float* __restrict__ S1, float* __restrict__ S2)
{
    __shared__ float lds_s1[4][32];
    __shared__ float lds_s2[4];

    const int lane = threadIdx.x & 63;
    const int wv   = threadIdx.x >> 6;
    const int lr   = lane & 15;
    const int kc   = lane >> 4;

    bf16x8 bfr[8][2];
    #pragma unroll
    for (int ct = 0; ct < 2; ++ct) {
        const float* wp = Wmat + (size_t)(ct * 16 + lr) * FEATS + kc * 8;
        #pragma unroll
        for (int kt = 0; kt < 8; ++kt) {
            f32x4 v0 = *(const f32x4*)(wp + kt * 32);
            f32x4 v1 = *(const f32x4*)(wp + kt * 32 + 4);
            bf16x8 b;
            b[0]=f2bf(v0.x); b[1]=f2bf(v0.y); b[2]=f2bf(v0.z); b[3]=f2bf(v0.w);
            b[4]=f2bf(v1.x); b[5]=f2bf(v1.y); b[6]=f2bf(v1.z); b[7]=f2bf(v1.w);
            bfr[kt][ct] = b;
        }
    }

    const float bias0 = bias[lr], bias1 = bias[16 + lr];
    const float invn = 1.0f / (float)N_NODES;
    float s1_0 = 0.f, s1_1 = 0.f, s2 = 0.f;

    const int ntiles = N_NODES / 16;
    for (int t = blockIdx.x * 4 + wv; t < ntiles; t += gridDim.x * 4) {
        const int base = t * 16;
        const float* xp = x + (size_t)(base + lr) * FEATS + kc * 8;
        f32x4 acc0 = {bias0, bias0, bias0, bias0};
        f32x4 acc1 = {bias1, bias1, bias1, bias1};
        #pragma unroll
        for (int kt = 0; kt < 8; ++kt) {
            f32x4 v0 = *(const f32x4*)(xp + kt * 32);
            f32x4 v1 = *(const f32x4*)(xp + kt * 32 + 4);
            bf16x8 a;
            a[0]=f2bf(v0.x); a[1]=f2bf(v0.y); a[2]=f2bf(v0.z); a[3]=f2bf(v0.w);
            a[4]=f2bf(v1.x); a[5]=f2bf(v1.y); a[6]=f2bf(v1.z); a[7]=f2bf(v1.w);
            acc0 = __builtin_amdgcn_mfma_f32_16x16x32_bf16(a, bfr[kt][0], acc0, 0, 0, 0);
            acc1 = __builtin_amdgcn_mfma_f32_16x16x32_bf16(a, bfr[kt][1], acc1, 0, 0, 0);
        }
        #pragma unroll
        for (int i = 0; i < 4; ++i) {
            const int row = base + kc * 4 + i;
            h[(size_t)row * NC + lr]      = acc0[i];
            h[(size_t)row * NC + 16 + lr] = acc1[i];
            const float um = u_sum[row] * invn;
            float a0 = um * acc0[i], a1 = um * acc1[i];
            s1_0 += a0; s1_1 += a1;
            s2 += a0 * a0 + a1 * a1;
        }
    }

    s1_0 += __shfl_xor(s1_0, 16); s1_0 += __shfl_xor(s1_0, 32);
    s1_1 += __shfl_xor(s1_1, 16); s1_1 += __shfl_xor(s1_1, 32);
    #pragma unroll
    for (int off = 1; off < 64; off <<= 1) s2 += __shfl_xor(s2, off);
    if (lane < 16) { lds_s1[wv][lr] = s1_0; lds_s1[wv][16 + lr] = s1_1; }
    if (lane == 0) lds_s2[wv] = s2;
    __syncthreads();
    if (threadIdx.x < 32) {
        float t4 = lds_s1[0][threadIdx.x] + lds_s1[1][threadIdx.x]
                 + lds_s1[2][threadIdx.x] + lds_s1[3][threadIdx.x];
        atomAddF(&S1[threadIdx.x], t4);
    }
    if (threadIdx.x == 32)
        atomAddF(S2, lds_s2[0] + lds_s2[1] + lds_s2[2] + lds_s2[3]);
}

// ---------------------------------------------------------------------------
// Bucketing: count -> scan -> multisplit scatter. int4 edge loads.
// ---------------------------------------------------------------------------
__global__ __launch_bounds__(512) void k_count(
    const int* __restrict__ dst, int* __restrict__ cnt)
{
    __shared__ int hist[BUCKETS];
    for (int i = threadIdx.x; i < BUCKETS; i += 512) hist[i] = 0;
    __syncthreads();
    const int E4 = N_EDGES / 4;              // 800000
    const int tile = blockIdx.x * 2048;
    #pragma unroll
    for (int i = 0; i < 4; ++i) {
        int e4 = tile + i * 512 + threadIdx.x;
        if (e4 < E4) {
            int4 d = ((const int4*)dst)[e4];
            atomicAdd(&hist[d.x >> 8], 1);
            atomicAdd(&hist[d.y >> 8], 1);
            atomicAdd(&hist[d.z >> 8], 1);
            atomicAdd(&hist[d.w >> 8], 1);
        }
    }
    __syncthreads();
    for (int i = threadIdx.x; i < BUCKETS; i += 512)
        if (hist[i]) atomicAdd(&cnt[i], hist[i]);
}

__global__ __launch_bounds__(1024) void k_bscan(
    const int* __restrict__ cnt, int* __restrict__ base, int* __restrict__ pos)
{
    __shared__ int sm[1024];
    int v = (threadIdx.x < BUCKETS) ? cnt[threadIdx.x] : 0;
    sm[threadIdx.x] = v;
    __syncthreads();
    for (int off = 1; off < 1024; off <<= 1) {
        int t = (threadIdx.x >= off) ? sm[threadIdx.x - off] : 0;
        __syncthreads();
        sm[threadIdx.x] += t;
        __syncthreads();
    }
    if (threadIdx.x < BUCKETS) {
        int b = sm[threadIdx.x] - v;
        base[threadIdx.x] = b;
        pos[threadIdx.x]  = b;
    }
}

// payload: x = src | (dst&255)<<18  (src < 2^18), y = w bits
__global__ __launch_bounds__(512) void k_bucket(
    const int* __restrict__ src, const float* __restrict__ w,
    const int* __restrict__ dst, int* __restrict__ pos,
    int2* __restrict__ bucketed)
{
    __shared__ int hist[BUCKETS];
    __shared__ int cursor[BUCKETS];
    for (int i = threadIdx.x; i < BUCKETS; i += 512) hist[i] = 0;
    __syncthreads();

    const int E4 = N_EDGES / 4;
    const int tile = blockIdx.x * 2048;
    int4 dd[4];
    #pragma unroll
    for (int i = 0; i < 4; ++i) {
        int e4 = tile + i * 512 + threadIdx.x;
        if (e4 < E4) {
            int4 d = ((const int4*)dst)[e4];
            dd[i] = d;
            atomicAdd(&hist[d.x >> 8], 1);
            atomicAdd(&hist[d.y >> 8], 1);
            atomicAdd(&hist[d.z >> 8], 1);
            atomicAdd(&hist[d.w >> 8], 1);
        } else dd[i].x = -1;
    }
    __syncthreads();
    for (int i = threadIdx.x; i < BUCKETS; i += 512) {
        int hc = hist[i];
        cursor[i] = hc ? atomicAdd(&pos[i], hc) : 0;
    }
    __syncthreads();
    #pragma unroll
    for (int i = 0; i < 4; ++i) {
        int e4 = tile + i * 512 + threadIdx.x;
        if (dd[i].x >= 0) {
            int4   s4 = ((const int4*)src)[e4];
            float4 w4 = ((const float4*)w)[e4];
            int d, p; int2 v;
            d = dd[i].x; p = atomicAdd(&cursor[d >> 8], 1);
            v.x = s4.x | ((d & (NBPB - 1)) << 18); v.y = __float_as_int(w4.x);
            bucketed[p] = v;
            d = dd[i].y; p = atomicAdd(&cursor[d >> 8], 1);
            v.x = s4.y | ((d & (NBPB - 1)) << 18); v.y = __float_as_int(w4.y);
            bucketed[p] = v;
            d = dd[i].z; p = atomicAdd(&cursor[d >> 8], 1);
            v.x = s4.z | ((d & (NBPB - 1)) << 18); v.y = __float_as_int(w4.z);
            bucketed[p] = v;
            d = dd[i].w; p = atomicAdd(&cursor[d >> 8], 1);
            v.x = s4.w | ((d & (NBPB - 1)) << 18); v.y = __float_as_int(w4.w);
            bucketed[p] = v;
        }
    }
}

// ---------------------------------------------------------------------------
// Per-bucket reduce: one THREAD per edge (full 128 B h-row via 8 independent
// dwordx4), payload prefetched one stride ahead, sched_barrier pins the load
// group above the atomic group. ych stride-33 padded. No hot-loop barriers.
// ---------------------------------------------------------------------------
__global__ __launch_bounds__(512) void k_breduce(
    const int2* __restrict__ bucketed, const int* __restrict__ base,
    const int* __restrict__ cnt, const float* __restrict__ h,
    float* __restrict__ y, float* __restrict__ colsum)
{
    __shared__ float ych[NBPB * YSTRIDE];   // 33.8 KB
    __shared__ float red[512];
    const int b = blockIdx.x;

    for (int i = threadIdx.x; i < NBPB * YSTRIDE; i += 512) ych[i] = 0.f;
    __syncthreads();

    const int beg = base[b], n = cnt[b];
    int idx = threadIdx.x;
    int2 p;
    if (idx < n) p = bucketed[beg + idx];
    while (idx < n) {
        const int nidx = idx + 512;
        int2 pn;
        if (nidx < n) pn = bucketed[beg + nidx];
        else { pn.x = 0; pn.y = 0; }

        const int   node = p.x & 0x3FFFF;
        const int   ld   = (int)((unsigned)p.x >> 18);
        const float wv   = __int_as_float(p.y);
        const f32x4* hp  = (const f32x4*)(h + (size_t)node * NC);
        f32x4 a[8];
        #pragma unroll
        for (int m = 0; m < 8; ++m) a[m] = hp[m];
        __builtin_amdgcn_sched_barrier(0);  // keep all 8 loads issued first

        float* yr = &ych[ld * YSTRIDE];
        #pragma unroll
        for (int m = 0; m < 8; ++m) {
            atomicAdd(&yr[m * 4 + 0], a[m].x * wv);
            atomicAdd(&yr[m * 4 + 1], a[m].y * wv);
            atomicAdd(&yr[m * 4 + 2], a[m].z * wv);
            atomicAdd(&yr[m * 4 + 3], a[m].w * wv);
        }
        p = pn;
        idx = nidx;
    }
    __syncthreads();

    const int node0 = b * NBPB;
    const int nn = (N_NODES - node0 < NBPB) ? (N_NODES - node0) : NBPB;
    float scol = 0.f;
    for (int i = threadIdx.x; i < nn * NC; i += 512) {   // i&31 const per thread
        float v = ych[(i >> 5) * YSTRIDE + (i & 31)];
        y[(size_t)node0 * NC + i] = v;
        scol += v;
    }

    red[threadIdx.x] = scol;
    __syncthreads();
    if (threadIdx.x < 32) {
        float t = 0.f;
        #pragma unroll
        for (int jj = 0; jj < 16; ++jj) t += red[threadIdx.x + 32 * jj];
        atomAddF(&colsum[threadIdx.x], t);
    }
}

// ---------------------------------------------------------------------------
// Fallback path (small workspace)
// ---------------------------------------------------------------------------
__global__ __launch_bounds__(256) void k_scatter_atomic(
    const float* __restrict__ h, const float* __restrict__ w,
    const int* __restrict__ src, const int* __restrict__ dst,
    float* __restrict__ y)
{
    const long long total  = (long long)N_EDGES * NC;
    const long long stride = (long long)gridDim.x * 256;
    for (long long i = (long long)blockIdx.x * 256 + threadIdx.x;
         i < total; i += stride) {
        const int e = (int)(i >> 5);
        const int c = (int)(i & 31);
        atomAddF(&y[(size_t)dst[e] * NC + c], h[(size_t)src[e] * NC + c] * w[e]);
    }
}

__global__ __launch_bounds__(256) void k_colsum(
    const float* __restrict__ y, float* __restrict__ colsum)
{
    __shared__ float red[256];
    const long long total  = (long long)N_NODES * NC;
    const long long stride = (long long)gridDim.x * 256;
    float s = 0.f;
    for (long long i = (long long)blockIdx.x * 256 + threadIdx.x;
         i < total; i += stride)
        s += y[i];
    red[threadIdx.x] = s;
    __syncthreads();
    if (threadIdx.x < 32) {
        float t = 0.f;
        #pragma unroll
        for (int j = 0; j < 8; ++j) t += red[threadIdx.x + 32 * j];
        atomAddF(&colsum[threadIdx.x], t);
    }
}

// ---------------------------------------------------------------------------
// loss; acc: [0..31] colsum_y, [32..63] S1, [64] S2
// ---------------------------------------------------------------------------
__global__ void k_final(const float* __restrict__ acc, float* __restrict__ loss_out)
{
    double cross = 0.0, msq = 0.0;
    for (int c = 0; c < NC; ++c) {
        double m = (double)acc[c] / (double)N_NODES;
        cross += m * (double)acc[32 + c];
        msq   += m * m;
    }
    double loss = ((double)acc[64] - 2.0 * cross + (double)N_NODES * msq)
                  / ((double)N_NODES * (double)NC);
    *loss_out = (float)loss;
}

extern "C" void kernel_launch(void* const* d_in, const int* in_sizes, int n_in,
                              void* d_out, int out_size, void* d_ws, size_t ws_size,
                              hipStream_t stream)
{
    const float* x   = (const float*)d_in[0];
    const float* w   = (const float*)d_in[1];
    const float* u   = (const float*)d_in[2];
    const float* Wm  = (const float*)d_in[3];
    const float* Wb  = (const float*)d_in[4];
    const int*   src = (const int*)d_in[5];
    const int*   dst = (const int*)d_in[6];

    float* out = (float*)d_out;                  // y [N*32] then loss [1]

    uint8_t* w8 = (uint8_t*)d_ws;
    float* acc  = (float*)w8;                    // 256 floats
    int*   cnt  = (int*)(w8 + 1024);             // BUCKETS (padded 1024)
    int*   base = cnt + 1024;
    int*   pos  = base + 1024;
    float* h    = (float*)(pos + 1024);          // 25.6 MB (128B-aligned)
    int2*  bucketed = (int2*)(h + (size_t)N_NODES * NC);  // 25.6 MB

    const size_t need = 1024 + 3 * 1024 * 4
                      + (size_t)N_NODES * NC * 4 + (size_t)N_EDGES * 8;

    hipMemsetAsync(acc, 0, 256 * sizeof(float), stream);

    const int NBK = (N_EDGES / 4 + 2047) / 2048; // 391

    if (ws_size >= need) {
        hipMemsetAsync(cnt, 0, BUCKETS * sizeof(int), stream);

        k_linear <<<1024, 256, 0, stream>>>(x, Wm, Wb, u, h, acc + 32, acc + 64);
        k_count  <<<NBK, 512, 0, stream>>>(dst, cnt);
        k_bscan  <<<1, 1024, 0, stream>>>(cnt, base, pos);
        k_bucket <<<NBK, 512, 0, stream>>>(src, w, dst, pos, bucketed);
        k_breduce<<<BUCKETS, 512, 0, stream>>>(bucketed, base, cnt, h, out, acc);
    } else {
        float* h2 = (float*)w8 + 256;
        hipMemsetAsync(d_out, 0, (size_t)out_size * sizeof(float), stream);
        k_linear        <<<1024, 256, 0, stream>>>(x, Wm, Wb, u, h2, acc + 32, acc + 64);
        k_scatter_atomic<<<8192, 256, 0, stream>>>(h2, w, src, dst, out);
        k_colsum        <<<2048, 256, 0, stream>>>(out, acc);
    }

    k_final<<<1, 1, 0, stream>>>(acc, out + (size_t)N_NODES * NC);
}

// Round 7
// 789.414 us; speedup vs baseline: 1.1527x; 1.0448x over previous
//
#include <hip/hip_runtime.h>
#include <hip/hip_bf16.h>

#define N_NODES 200000
#define N_EDGES 3200000
#define FEATS   256
#define NC      32

#define NBPB    128                      // nodes per bucket (dst >> 7)
#define BUCKETS 1563                     // ceil(200000 / 128)
#define CAP     2560                     // edges per bucket capacity (mean 2047, 11 sigma)

typedef __attribute__((ext_vector_type(8))) short bf16x8;
typedef __attribute__((ext_vector_type(4))) float f32x4;

__device__ __forceinline__ float atomAddF(float* p, float v) {
    return unsafeAtomicAdd(p, v);
}
__device__ __forceinline__ short f2bf(float f) {
    return (short)__bfloat16_as_ushort(__float2bfloat16(f));
}

// ---------------------------------------------------------------------------
// init: acc[0..255] = 0, pos[b] = b*CAP
// ---------------------------------------------------------------------------
__global__ __launch_bounds__(256) void k_init(float* acc, int* pos)
{
    int i = blockIdx.x * 256 + threadIdx.x;
    if (i < 256) acc[i] = 0.f;
    if (i < BUCKETS) pos[i] = i * CAP;
}

// ---------------------------------------------------------------------------
// Kernel 1: h = x @ W^T + bias via bf16 MFMA; h stored as BF16 (the only
// consumer is the edge-gather; halves gather line traffic).
// Fused: S1[c] += (u[n]/N)*h[n,c], S2 += (...)^2  (f32 from registers).
// ---------------------------------------------------------------------------
__global__ __launch_bounds__(256, 3) void k_linear(
    const float* __restrict__ x, const float* __restrict__ Wmat,
    const float* __restrict__ bias, const float* __restrict__ u_sum,
    ushort* __restrict__ h_bf, float* __restrict__ S1, float* __restrict__ S2)
{
    __shared__ float lds_s1[4][32];
    __shared__ float lds_s2[4];

    const int lane = threadIdx.x & 63;
    const int wv   = threadIdx.x >> 6;
    const int lr   = lane & 15;
    const int kc   = lane >> 4;

    bf16x8 bfr[8][2];
    #pragma unroll
    for (int ct = 0; ct < 2; ++ct) {
        const float* wp = Wmat + (size_t)(ct * 16 + lr) * FEATS + kc * 8;
        #pragma unroll
        for (int kt = 0; kt < 8; ++kt) {
            f32x4 v0 = *(const f32x4*)(wp + kt * 32);
            f32x4 v1 = *(const f32x4*)(wp + kt * 32 + 4);
            bf16x8 b;
            b[0]=f2bf(v0.x); b[1]=f2bf(v0.y); b[2]=f2bf(v0.z); b[3]=f2bf(v0.w);
            b[4]=f2bf(v1.x); b[5]=f2bf(v1.y); b[6]=f2bf(v1.z); b[7]=f2bf(v1.w);
            bfr[kt][ct] = b;
        }
    }

    const float bias0 = bias[lr], bias1 = bias[16 + lr];
    const float invn = 1.0f / (float)N_NODES;
    float s1_0 = 0.f, s1_1 = 0.f, s2 = 0.f;

    const int ntiles = N_NODES / 16;
    for (int t = blockIdx.x * 4 + wv; t < ntiles; t += gridDim.x * 4) {
        const int base = t * 16;
        const float* xp = x + (size_t)(base + lr) * FEATS + kc * 8;
        f32x4 acc0 = {bias0, bias0, bias0, bias0};
        f32x4 acc1 = {bias1, bias1, bias1, bias1};
        #pragma unroll
        for (int kt = 0; kt < 8; ++kt) {
            f32x4 v0 = *(const f32x4*)(xp + kt * 32);
            f32x4 v1 = *(const f32x4*)(xp + kt * 32 + 4);
            bf16x8 a;
            a[0]=f2bf(v0.x); a[1]=f2bf(v0.y); a[2]=f2bf(v0.z); a[3]=f2bf(v0.w);
            a[4]=f2bf(v1.x); a[5]=f2bf(v1.y); a[6]=f2bf(v1.z); a[7]=f2bf(v1.w);
            acc0 = __builtin_amdgcn_mfma_f32_16x16x32_bf16(a, bfr[kt][0], acc0, 0, 0, 0);
            acc1 = __builtin_amdgcn_mfma_f32_16x16x32_bf16(a, bfr[kt][1], acc1, 0, 0, 0);
        }
        #pragma unroll
        for (int i = 0; i < 4; ++i) {
            const int row = base + kc * 4 + i;
            h_bf[(size_t)row * NC + lr]      = (ushort)f2bf(acc0[i]);
            h_bf[(size_t)row * NC + 16 + lr] = (ushort)f2bf(acc1[i]);
            const float um = u_sum[row] * invn;
            float a0 = um * acc0[i], a1 = um * acc1[i];
            s1_0 += a0; s1_1 += a1;
            s2 += a0 * a0 + a1 * a1;
        }
    }

    s1_0 += __shfl_xor(s1_0, 16); s1_0 += __shfl_xor(s1_0, 32);
    s1_1 += __shfl_xor(s1_1, 16); s1_1 += __shfl_xor(s1_1, 32);
    #pragma unroll
    for (int off = 1; off < 64; off <<= 1) s2 += __shfl_xor(s2, off);
    if (lane < 16) { lds_s1[wv][lr] = s1_0; lds_s1[wv][16 + lr] = s1_1; }
    if (lane == 0) lds_s2[wv] = s2;
    __syncthreads();
    if (threadIdx.x < 32) {
        float t4 = lds_s1[0][threadIdx.x] + lds_s1[1][threadIdx.x]
                 + lds_s1[2][threadIdx.x] + lds_s1[3][threadIdx.x];
        atomAddF(&S1[threadIdx.x], t4);
    }
    if (threadIdx.x == 32)
        atomAddF(S2, lds_s2[0] + lds_s2[1] + lds_s2[2] + lds_s2[3]);
}

// ---------------------------------------------------------------------------
// Multisplit bucketing (single pass, fixed CAP per bucket).
// payload: x = src | (dst&127)<<18  (src < 2^18), y = w bits
// ---------------------------------------------------------------------------
__global__ __launch_bounds__(512) void k_bucket(
    const int* __restrict__ src, const float* __restrict__ w,
    const int* __restrict__ dst, int* __restrict__ pos,
    int2* __restrict__ bucketed)
{
    __shared__ int hist[BUCKETS];
    __shared__ int cursor[BUCKETS];
    for (int i = threadIdx.x; i < BUCKETS; i += 512) hist[i] = 0;
    __syncthreads();

    const int E4 = N_EDGES / 4;
    const int tile = blockIdx.x * 2048;
    int4 dd[4];
    #pragma unroll
    for (int i = 0; i < 4; ++i) {
        int e4 = tile + i * 512 + threadIdx.x;
        if (e4 < E4) {
            int4 d = ((const int4*)dst)[e4];
            dd[i] = d;
            atomicAdd(&hist[d.x >> 7], 1);
            atomicAdd(&hist[d.y >> 7], 1);
            atomicAdd(&hist[d.z >> 7], 1);
            atomicAdd(&hist[d.w >> 7], 1);
        } else dd[i].x = -1;
    }
    __syncthreads();
    for (int i = threadIdx.x; i < BUCKETS; i += 512) {
        int hc = hist[i];
        cursor[i] = hc ? atomicAdd(&pos[i], hc) : 0;
    }
    __syncthreads();
    #pragma unroll
    for (int i = 0; i < 4; ++i) {
        int e4 = tile + i * 512 + threadIdx.x;
        if (dd[i].x >= 0) {
            int4   s4 = ((const int4*)src)[e4];
            float4 w4 = ((const float4*)w)[e4];
            int d, p; int2 v;
            d = dd[i].x; p = atomicAdd(&cursor[d >> 7], 1);
            v.x = s4.x | ((d & (NBPB - 1)) << 18); v.y = __float_as_int(w4.x);
            bucketed[p] = v;
            d = dd[i].y; p = atomicAdd(&cursor[d >> 7], 1);
            v.x = s4.y | ((d & (NBPB - 1)) << 18); v.y = __float_as_int(w4.y);
            bucketed[p] = v;
            d = dd[i].z; p = atomicAdd(&cursor[d >> 7], 1);
            v.x = s4.z | ((d & (NBPB - 1)) << 18); v.y = __float_as_int(w4.z);
            bucketed[p] = v;
            d = dd[i].w; p = atomicAdd(&cursor[d >> 7], 1);
            v.x = s4.w | ((d & (NBPB - 1)) << 18); v.y = __float_as_int(w4.w);
            bucketed[p] = v;
        }
    }
}

// ---------------------------------------------------------------------------
// Per-bucket reduce, channel-parallel: 32 lanes per edge, ONE 64B line per
// edge (bf16 h row), ds_add into ych (stride 32 -> bank==channel,
// conflict-free). 256-thread blocks, 16KB ych -> ~6 blocks/CU.
// ---------------------------------------------------------------------------
__global__ __launch_bounds__(256) void k_breduce(
    const int2* __restrict__ bucketed, const int* __restrict__ pos,
    const ushort* __restrict__ h_bf,
    float* __restrict__ y, float* __restrict__ colsum)
{
    __shared__ float ych[NBPB * NC];     // 16 KB
    __shared__ float red[256];
    const int b = blockIdx.x;
    const int c = threadIdx.x & 31;      // channel == segment lane
    const int g = threadIdx.x >> 5;      // 0..7

    for (int i = threadIdx.x; i < NBPB * NC; i += 256) ych[i] = 0.f;
    __syncthreads();

    const __hip_bfloat16* hb = (const __hip_bfloat16*)h_bf;
    const int beg = b * CAP;
    const int n = pos[b] - beg;

    for (int ch = g * 32; ch < n; ch += 256) {
        const int idx = ch + c;
        int2 p;
        if (idx < n) p = bucketed[beg + idx];
        else { p.x = 0; p.y = 0; }       // sentinel: w=0 adds 0 to row 0

        #pragma unroll
        for (int j0 = 0; j0 < 32; j0 += 8) {
            int   px0 = __shfl(p.x, j0 + 0, 32), py0 = __shfl(p.y, j0 + 0, 32);
            int   px1 = __shfl(p.x, j0 + 1, 32), py1 = __shfl(p.y, j0 + 1, 32);
            int   px2 = __shfl(p.x, j0 + 2, 32), py2 = __shfl(p.y, j0 + 2, 32);
            int   px3 = __shfl(p.x, j0 + 3, 32), py3 = __shfl(p.y, j0 + 3, 32);
            int   px4 = __shfl(p.x, j0 + 4, 32), py4 = __shfl(p.y, j0 + 4, 32);
            int   px5 = __shfl(p.x, j0 + 5, 32), py5 = __shfl(p.y, j0 + 5, 32);
            int   px6 = __shfl(p.x, j0 + 6, 32), py6 = __shfl(p.y, j0 + 6, 32);
            int   px7 = __shfl(p.x, j0 + 7, 32), py7 = __shfl(p.y, j0 + 7, 32);
            float h0 = __bfloat162float(hb[(size_t)(px0 & 0x3FFFF) * NC + c]);
            float h1 = __bfloat162float(hb[(size_t)(px1 & 0x3FFFF) * NC + c]);
            float h2 = __bfloat162float(hb[(size_t)(px2 & 0x3FFFF) * NC + c]);
            float h3 = __bfloat162float(hb[(size_t)(px3 & 0x3FFFF) * NC + c]);
            float h4 = __bfloat162float(hb[(size_t)(px4 & 0x3FFFF) * NC + c]);
            float h5 = __bfloat162float(hb[(size_t)(px5 & 0x3FFFF) * NC + c]);
            float h6 = __bfloat162float(hb[(size_t)(px6 & 0x3FFFF) * NC + c]);
            float h7 = __bfloat162float(hb[(size_t)(px7 & 0x3FFFF) * NC + c]);
            __builtin_amdgcn_sched_barrier(0);
            atomicAdd(&ych[(((unsigned)px0) >> 18) * NC + c], h0 * __int_as_float(py0));
            atomicAdd(&ych[(((unsigned)px1) >> 18) * NC + c], h1 * __int_as_float(py1));
            atomicAdd(&ych[(((unsigned)px2) >> 18) * NC + c], h2 * __int_as_float(py2));
            atomicAdd(&ych[(((unsigned)px3) >> 18) * NC + c], h3 * __int_as_float(py3));
            atomicAdd(&ych[(((unsigned)px4) >> 18) * NC + c], h4 * __int_as_float(py4));
            atomicAdd(&ych[(((unsigned)px5) >> 18) * NC + c], h5 * __int_as_float(py5));
            atomicAdd(&ych[(((unsigned)px6) >> 18) * NC + c], h6 * __int_as_float(py6));
            atomicAdd(&ych[(((unsigned)px7) >> 18) * NC + c], h7 * __int_as_float(py7));
        }
    }
    __syncthreads();

    const int node0 = b * NBPB;
    const int nn = (N_NODES - node0 < NBPB) ? (N_NODES - node0) : NBPB;
    float scol = 0.f;
    for (int i = threadIdx.x; i < nn * NC; i += 256) {   // i&31 const per thread
        float v = ych[i];
        y[(size_t)node0 * NC + i] = v;
        scol += v;
    }

    red[threadIdx.x] = scol;
    __syncthreads();
    if (threadIdx.x < 32) {
        float t = 0.f;
        #pragma unroll
        for (int jj = 0; jj < 8; ++jj) t += red[threadIdx.x + 32 * jj];
        atomAddF(&colsum[threadIdx.x], t);
    }
}

// ---------------------------------------------------------------------------
// Fallback path (small workspace)
// ---------------------------------------------------------------------------
__global__ __launch_bounds__(256) void k_scatter_atomic(
    const ushort* __restrict__ h_bf, const float* __restrict__ w,
    const int* __restrict__ src, const int* __restrict__ dst,
    float* __restrict__ y)
{
    const __hip_bfloat16* hb = (const __hip_bfloat16*)h_bf;
    const long long total  = (long long)N_EDGES * NC;
    const long long stride = (long long)gridDim.x * 256;
    for (long long i = (long long)blockIdx.x * 256 + threadIdx.x;
         i < total; i += stride) {
        const int e = (int)(i >> 5);
        const int c = (int)(i & 31);
        float hv = __bfloat162float(hb[(size_t)src[e] * NC + c]);
        atomAddF(&y[(size_t)dst[e] * NC + c], hv * w[e]);
    }
}

__global__ __launch_bounds__(256) void k_colsum(
    const float* __restrict__ y, float* __restrict__ colsum)
{
    __shared__ float red[256];
    const long long total  = (long long)N_NODES * NC;
    const long long stride = (long long)gridDim.x * 256;
    float s = 0.f;
    for (long long i = (long long)blockIdx.x * 256 + threadIdx.x;
         i < total; i += stride)
        s += y[i];
    red[threadIdx.x] = s;
    __syncthreads();
    if (threadIdx.x < 32) {
        float t = 0.f;
        #pragma unroll
        for (int j = 0; j < 8; ++j) t += red[threadIdx.x + 32 * j];
        atomAddF(&colsum[threadIdx.x], t);
    }
}

// ---------------------------------------------------------------------------
// loss; acc: [0..31] colsum_y, [32..63] S1, [64] S2
// ---------------------------------------------------------------------------
__global__ void k_final(const float* __restrict__ acc, float* __restrict__ loss_out)
{
    double cross = 0.0, msq = 0.0;
    for (int c = 0; c < NC; ++c) {
        double m = (double)acc[c] / (double)N_NODES;
        cross += m * (double)acc[32 + c];
        msq   += m * m;
    }
    double loss = ((double)acc[64] - 2.0 * cross + (double)N_NODES * msq)
                  / ((double)N_NODES * (double)NC);
    *loss_out = (float)loss;
}

extern "C" void kernel_launch(void* const* d_in, const int* in_sizes, int n_in,
                              void* d_out, int out_size, void* d_ws, size_t ws_size,
                              hipStream_t stream)
{
    const float* x   = (const float*)d_in[0];
    const float* w   = (const float*)d_in[1];
    const float* u   = (const float*)d_in[2];
    const float* Wm  = (const float*)d_in[3];
    const float* Wb  = (const float*)d_in[4];
    const int*   src = (const int*)d_in[5];
    const int*   dst = (const int*)d_in[6];

    float* out = (float*)d_out;                  // y [N*32] then loss [1]

    uint8_t* w8 = (uint8_t*)d_ws;
    float*  acc  = (float*)w8;                   // 256 floats (1 KB)
    int*    pos  = (int*)(w8 + 1024);            // BUCKETS (padded 2048)
    ushort* h_bf = (ushort*)(w8 + 1024 + 8192);  // 12.8 MB
    int2*   bucketed = (int2*)(w8 + 1024 + 8192 + (size_t)N_NODES * NC * 2); // 32 MB

    const size_t need = 1024 + 8192 + (size_t)N_NODES * NC * 2
                      + (size_t)BUCKETS * CAP * 8;

    if (ws_size >= need) {
        k_init   <<<8, 256, 0, stream>>>(acc, pos);
        k_linear <<<1024, 256, 0, stream>>>(x, Wm, Wb, u, h_bf, acc + 32, acc + 64);
        const int NBK = (N_EDGES / 4 + 2047) / 2048;  // 391
        k_bucket <<<NBK, 512, 0, stream>>>(src, w, dst, pos, bucketed);
        k_breduce<<<BUCKETS, 256, 0, stream>>>(bucketed, pos, h_bf, out, acc);
    } else {
        k_init<<<8, 256, 0, stream>>>(acc, pos);
        hipMemsetAsync(d_out, 0, (size_t)out_size * sizeof(float), stream);
        k_linear        <<<1024, 256, 0, stream>>>(x, Wm, Wb, u, h_bf, acc + 32, acc + 64);
        k_scatter_atomic<<<8192, 256, 0, stream>>>(h_bf, w, src, dst, out);
        k_colsum        <<<2048, 256, 0, stream>>>(out, acc);
    }

    k_final<<<1, 1, 0, stream>>>(acc, out + (size_t)N_NODES * NC);
}

// Round 8
// 284.517 us; speedup vs baseline: 3.1983x; 2.7746x over previous
//
#include <hip/hip_runtime.h>
#include <hip/hip_bf16.h>

#define N_NODES 200000
#define N_EDGES 3200000
#define FEATS   256
#define NC      32

#define NBPB    128                      // nodes per bucket (dst >> 7)
#define BUCKETS 1563                     // ceil(200000 / 128)
#define CAP     2560                     // bucket capacity (mean 2047, +11 sigma)

typedef __attribute__((ext_vector_type(8))) short bf16x8;
typedef __attribute__((ext_vector_type(4))) float f32x4;

__device__ __forceinline__ float atomAddF(float* p, float v) {
    return unsafeAtomicAdd(p, v);
}
__device__ __forceinline__ short f2bf(float f) {
    return (short)__bfloat16_as_ushort(__float2bfloat16(f));
}

// ---------------------------------------------------------------------------
// init: acc[0..255] = 0, pos[b] = b*CAP
// ---------------------------------------------------------------------------
__global__ __launch_bounds__(256) void k_init(float* acc, int* pos)
{
    int i = blockIdx.x * 256 + threadIdx.x;
    if (i < 256) acc[i] = 0.f;
    if (i < BUCKETS) pos[i] = i * CAP;
}

// ---------------------------------------------------------------------------
// Kernel 1: h = x @ W^T + bias via bf16 MFMA; h stored as BF16.
// Fused: S1[c] += (u[n]/N)*h[n,c], S2 += (...)^2  (f32 from registers).
// ---------------------------------------------------------------------------
__global__ __launch_bounds__(256, 3) void k_linear(
    const float* __restrict__ x, const float* __restrict__ Wmat,
    const float* __restrict__ bias, const float* __restrict__ u_sum,
    ushort* __restrict__ h_bf, float* __restrict__ S1, float* __restrict__ S2)
{
    __shared__ float lds_s1[4][32];
    __shared__ float lds_s2[4];

    const int lane = threadIdx.x & 63;
    const int wv   = threadIdx.x >> 6;
    const int lr   = lane & 15;
    const int kc   = lane >> 4;

    bf16x8 bfr[8][2];
    #pragma unroll
    for (int ct = 0; ct < 2; ++ct) {
        const float* wp = Wmat + (size_t)(ct * 16 + lr) * FEATS + kc * 8;
        #pragma unroll
        for (int kt = 0; kt < 8; ++kt) {
            f32x4 v0 = *(const f32x4*)(wp + kt * 32);
            f32x4 v1 = *(const f32x4*)(wp + kt * 32 + 4);
            bf16x8 b;
            b[0]=f2bf(v0.x); b[1]=f2bf(v0.y); b[2]=f2bf(v0.z); b[3]=f2bf(v0.w);
            b[4]=f2bf(v1.x); b[5]=f2bf(v1.y); b[6]=f2bf(v1.z); b[7]=f2bf(v1.w);
            bfr[kt][ct] = b;
        }
    }

    const float bias0 = bias[lr], bias1 = bias[16 + lr];
    const float invn = 1.0f / (float)N_NODES;
    float s1_0 = 0.f, s1_1 = 0.f, s2 = 0.f;

    const int ntiles = N_NODES / 16;
    for (int t = blockIdx.x * 4 + wv; t < ntiles; t += gridDim.x * 4) {
        const int base = t * 16;
        const float* xp = x + (size_t)(base + lr) * FEATS + kc * 8;
        f32x4 acc0 = {bias0, bias0, bias0, bias0};
        f32x4 acc1 = {bias1, bias1, bias1, bias1};
        #pragma unroll
        for (int kt = 0; kt < 8; ++kt) {
            f32x4 v0 = *(const f32x4*)(xp + kt * 32);
            f32x4 v1 = *(const f32x4*)(xp + kt * 32 + 4);
            bf16x8 a;
            a[0]=f2bf(v0.x); a[1]=f2bf(v0.y); a[2]=f2bf(v0.z); a[3]=f2bf(v0.w);
            a[4]=f2bf(v1.x); a[5]=f2bf(v1.y); a[6]=f2bf(v1.z); a[7]=f2bf(v1.w);
            acc0 = __builtin_amdgcn_mfma_f32_16x16x32_bf16(a, bfr[kt][0], acc0, 0, 0, 0);
            acc1 = __builtin_amdgcn_mfma_f32_16x16x32_bf16(a, bfr[kt][1], acc1, 0, 0, 0);
        }
        #pragma unroll
        for (int i = 0; i < 4; ++i) {
            const int row = base + kc * 4 + i;
            h_bf[(size_t)row * NC + lr]      = (ushort)f2bf(acc0[i]);
            h_bf[(size_t)row * NC + 16 + lr] = (ushort)f2bf(acc1[i]);
            const float um = u_sum[row] * invn;
            float a0 = um * acc0[i], a1 = um * acc1[i];
            s1_0 += a0; s1_1 += a1;
            s2 += a0 * a0 + a1 * a1;
        }
    }

    s1_0 += __shfl_xor(s1_0, 16); s1_0 += __shfl_xor(s1_0, 32);
    s1_1 += __shfl_xor(s1_1, 16); s1_1 += __shfl_xor(s1_1, 32);
    #pragma unroll
    for (int off = 1; off < 64; off <<= 1) s2 += __shfl_xor(s2, off);
    if (lane < 16) { lds_s1[wv][lr] = s1_0; lds_s1[wv][16 + lr] = s1_1; }
    if (lane == 0) lds_s2[wv] = s2;
    __syncthreads();
    if (threadIdx.x < 32) {
        float t4 = lds_s1[0][threadIdx.x] + lds_s1[1][threadIdx.x]
                 + lds_s1[2][threadIdx.x] + lds_s1[3][threadIdx.x];
        atomAddF(&S1[threadIdx.x], t4);
    }
    if (threadIdx.x == 32)
        atomAddF(S2, lds_s2[0] + lds_s2[1] + lds_s2[2] + lds_s2[3]);
}

// ---------------------------------------------------------------------------
// Multisplit bucketing (single pass, fixed CAP per bucket).
// payload: x = src | (dst&127)<<18  (src < 2^18), y = w bits
// ---------------------------------------------------------------------------
__global__ __launch_bounds__(512) void k_bucket(
    const int* __restrict__ src, const float* __restrict__ w,
    const int* __restrict__ dst, int* __restrict__ pos,
    int2* __restrict__ bucketed)
{
    __shared__ int hist[BUCKETS];
    __shared__ int cursor[BUCKETS];
    for (int i = threadIdx.x; i < BUCKETS; i += 512) hist[i] = 0;
    __syncthreads();

    const int E4 = N_EDGES / 4;
    const int tile = blockIdx.x * 2048;
    int4 dd[4];
    #pragma unroll
    for (int i = 0; i < 4; ++i) {
        int e4 = tile + i * 512 + threadIdx.x;
        if (e4 < E4) {
            int4 d = ((const int4*)dst)[e4];
            dd[i] = d;
            atomicAdd(&hist[d.x >> 7], 1);
            atomicAdd(&hist[d.y >> 7], 1);
            atomicAdd(&hist[d.z >> 7], 1);
            atomicAdd(&hist[d.w >> 7], 1);
        } else dd[i].x = -1;
    }
    __syncthreads();
    for (int i = threadIdx.x; i < BUCKETS; i += 512) {
        int hc = hist[i];
        cursor[i] = hc ? atomicAdd(&pos[i], hc) : 0;
    }
    __syncthreads();
    #pragma unroll
    for (int i = 0; i < 4; ++i) {
        int e4 = tile + i * 512 + threadIdx.x;
        if (dd[i].x >= 0) {
            int4   s4 = ((const int4*)src)[e4];
            float4 w4 = ((const float4*)w)[e4];
            int d, p; int2 v;
            d = dd[i].x; p = atomicAdd(&cursor[d >> 7], 1);
            v.x = s4.x | ((d & (NBPB - 1)) << 18); v.y = __float_as_int(w4.x);
            bucketed[p] = v;
            d = dd[i].y; p = atomicAdd(&cursor[d >> 7], 1);
            v.x = s4.y | ((d & (NBPB - 1)) << 18); v.y = __float_as_int(w4.y);
            bucketed[p] = v;
            d = dd[i].z; p = atomicAdd(&cursor[d >> 7], 1);
            v.x = s4.z | ((d & (NBPB - 1)) << 18); v.y = __float_as_int(w4.z);
            bucketed[p] = v;
            d = dd[i].w; p = atomicAdd(&cursor[d >> 7], 1);
            v.x = s4.w | ((d & (NBPB - 1)) << 18); v.y = __float_as_int(w4.w);
            bucketed[p] = v;
        }
    }
}

// ---------------------------------------------------------------------------
// Per-bucket: in-LDS counting sort to per-node CSR, then per-node register
// gather (16 groups x 32 channels). One 64B h-line per edge, y written once,
// colsum fused. ~24.6 KB LDS -> 4 blocks/CU (thread-limited) = full occupancy.
// ---------------------------------------------------------------------------
__global__ __launch_bounds__(512) void k_breduce(
    const int2* __restrict__ bucketed, const int* __restrict__ pos,
    const ushort* __restrict__ h_bf,
    float* __restrict__ y, float* __restrict__ colsum)
{
    __shared__ int2  eSort[CAP];         // 20 KB
    __shared__ int   scnt[NBPB];
    __shared__ int   soffs[NBPB];
    __shared__ int   scur[NBPB];
    __shared__ int   ssc[NBPB];
    __shared__ float red[512];

    const int tid = threadIdx.x;
    const int b   = blockIdx.x;
    const int beg = b * CAP;
    const int n   = pos[b] - beg;

    if (tid < NBPB) scnt[tid] = 0;
    __syncthreads();

    // 1) count local-dst occupancy
    for (int idx = tid; idx < n; idx += 512) {
        int2 p = bucketed[beg + idx];
        atomicAdd(&scnt[(unsigned)p.x >> 18], 1);
    }
    __syncthreads();

    // 2) exclusive scan over 128 counters (Hillis-Steele in LDS)
    if (tid < NBPB) ssc[tid] = scnt[tid];
    __syncthreads();
    for (int off = 1; off < NBPB; off <<= 1) {
        int t = 0;
        if (tid < NBPB && tid >= off) t = ssc[tid - off];
        __syncthreads();
        if (tid < NBPB && tid >= off) ssc[tid] += t;
        __syncthreads();
    }
    if (tid < NBPB) {
        int o = ssc[tid] - scnt[tid];
        soffs[tid] = o;
        scur[tid]  = o;
    }
    __syncthreads();

    // 3) scatter payloads into node-sorted LDS buffer
    for (int idx = tid; idx < n; idx += 512) {
        int2 p = bucketed[beg + idx];
        int q = atomicAdd(&scur[(unsigned)p.x >> 18], 1);
        eSort[q] = p;
    }
    __syncthreads();

    // 4) per-node gather: group g handles nodes ld = g, g+16, ...
    const __hip_bfloat16* hb = (const __hip_bfloat16*)h_bf;
    const int c = tid & 31;
    const int g = tid >> 5;              // 0..15
    float scol = 0.f;
    for (int ld = g; ld < NBPB; ld += 16) {
        const int node = b * NBPB + ld;
        if (node >= N_NODES) break;
        int j = soffs[ld];
        const int e = j + scnt[ld];
        float s = 0.f;
        int2 p;
        if (j < e) p = eSort[j];
        while (j < e) {
            int2 pn;
            if (j + 1 < e) pn = eSort[j + 1];       // prefetch next payload
            float hv = __bfloat162float(hb[(size_t)(p.x & 0x3FFFF) * NC + c]);
            s = fmaf(hv, __int_as_float(p.y), s);
            p = pn;
            ++j;
        }
        y[(size_t)node * NC + c] = s;
        scol += s;
    }

    red[tid] = scol;
    __syncthreads();
    if (tid < 32) {
        float t = 0.f;
        #pragma unroll
        for (int jj = 0; jj < 16; ++jj) t += red[tid + 32 * jj];
        atomAddF(&colsum[tid], t);
    }
}

// ---------------------------------------------------------------------------
// Fallback path (small workspace)
// ---------------------------------------------------------------------------
__global__ __launch_bounds__(256) void k_scatter_atomic(
    const ushort* __restrict__ h_bf, const float* __restrict__ w,
    const int* __restrict__ src, const int* __restrict__ dst,
    float* __restrict__ y)
{
    const __hip_bfloat16* hb = (const __hip_bfloat16*)h_bf;
    const long long total  = (long long)N_EDGES * NC;
    const long long stride = (long long)gridDim.x * 256;
    for (long long i = (long long)blockIdx.x * 256 + threadIdx.x;
         i < total; i += stride) {
        const int e = (int)(i >> 5);
        const int c = (int)(i & 31);
        float hv = __bfloat162float(hb[(size_t)src[e] * NC + c]);
        atomAddF(&y[(size_t)dst[e] * NC + c], hv * w[e]);
    }
}

__global__ __launch_bounds__(256) void k_colsum(
    const float* __restrict__ y, float* __restrict__ colsum)
{
    __shared__ float red[256];
    const long long total  = (long long)N_NODES * NC;
    const long long stride = (long long)gridDim.x * 256;
    float s = 0.f;
    for (long long i = (long long)blockIdx.x * 256 + threadIdx.x;
         i < total; i += stride)
        s += y[i];
    red[threadIdx.x] = s;
    __syncthreads();
    if (threadIdx.x < 32) {
        float t = 0.f;
        #pragma unroll
        for (int j = 0; j < 8; ++j) t += red[threadIdx.x + 32 * j];
        atomAddF(&colsum[threadIdx.x], t);
    }
}

// ---------------------------------------------------------------------------
// loss; acc: [0..31] colsum_y, [32..63] S1, [64] S2
// ---------------------------------------------------------------------------
__global__ void k_final(const float* __restrict__ acc, float* __restrict__ loss_out)
{
    double cross = 0.0, msq = 0.0;
    for (int c = 0; c < NC; ++c) {
        double m = (double)acc[c] / (double)N_NODES;
        cross += m * (double)acc[32 + c];
        msq   += m * m;
    }
    double loss = ((double)acc[64] - 2.0 * cross + (double)N_NODES * msq)
                  / ((double)N_NODES * (double)NC);
    *loss_out = (float)loss;
}

extern "C" void kernel_launch(void* const* d_in, const int* in_sizes, int n_in,
                              void* d_out, int out_size, void* d_ws, size_t ws_size,
                              hipStream_t stream)
{
    const float* x   = (const float*)d_in[0];
    const float* w   = (const float*)d_in[1];
    const float* u   = (const float*)d_in[2];
    const float* Wm  = (const float*)d_in[3];
    const float* Wb  = (const float*)d_in[4];
    const int*   src = (const int*)d_in[5];
    const int*   dst = (const int*)d_in[6];

    float* out = (float*)d_out;                  // y [N*32] then loss [1]

    uint8_t* w8 = (uint8_t*)d_ws;
    float*  acc  = (float*)w8;                   // 256 floats (1 KB)
    int*    pos  = (int*)(w8 + 1024);            // BUCKETS (padded 8 KB)
    ushort* h_bf = (ushort*)(w8 + 1024 + 8192);  // 12.8 MB
    int2*   bucketed = (int2*)(w8 + 1024 + 8192 + (size_t)N_NODES * NC * 2); // 32 MB

    const size_t need = 1024 + 8192 + (size_t)N_NODES * NC * 2
                      + (size_t)BUCKETS * CAP * 8;

    if (ws_size >= need) {
        k_init   <<<8, 256, 0, stream>>>(acc, pos);
        k_linear <<<1024, 256, 0, stream>>>(x, Wm, Wb, u, h_bf, acc + 32, acc + 64);
        const int NBK = (N_EDGES / 4 + 2047) / 2048;  // 391
        k_bucket <<<NBK, 512, 0, stream>>>(src, w, dst, pos, bucketed);
        k_breduce<<<BUCKETS, 512, 0, stream>>>(bucketed, pos, h_bf, out, acc);
    } else {
        k_init<<<8, 256, 0, stream>>>(acc, pos);
        hipMemsetAsync(d_out, 0, (size_t)out_size * sizeof(float), stream);
        k_linear        <<<1024, 256, 0, stream>>>(x, Wm, Wb, u, h_bf, acc + 32, acc + 64);
        k_scatter_atomic<<<8192, 256, 0, stream>>>(h_bf, w, src, dst, out);
        k_colsum        <<<2048, 256, 0, stream>>>(out, acc);
    }

    k_final<<<1, 1, 0, stream>>>(acc, out + (size_t)N_NODES * NC);
}

// Round 9
// 195.682 us; speedup vs baseline: 4.6503x; 1.4540x over previous
//
#include <hip/hip_runtime.h>
#include <hip/hip_bf16.h>

#define N_NODES 200000
#define N_EDGES 3200000
#define FEATS   256
#define NC      32

#define NBPB    128                      // nodes per bucket (dst >> 7)
#define BUCKETS 1563                     // ceil(200000 / 128)
#define CAP     2560                     // bucket capacity = 5*512 (mean 2047, +11 sigma)

#define BKT_BLOCKS 391                   // bucket tiles of 8192 edges
#define LIN_BLOCKS 512                   // linear blocks (8 waves each)

typedef __attribute__((ext_vector_type(8))) short bf16x8;
typedef __attribute__((ext_vector_type(4))) float f32x4;

__device__ __forceinline__ float atomAddF(float* p, float v) {
    return unsafeAtomicAdd(p, v);
}
__device__ __forceinline__ short f2bf(float f) {
    return (short)__bfloat16_as_ushort(__float2bfloat16(f));
}

// ---------------------------------------------------------------------------
// init: acc[0..255] = 0, pos[b] = b*CAP
// ---------------------------------------------------------------------------
__global__ __launch_bounds__(256) void k_init(float* acc, int* pos)
{
    int i = blockIdx.x * 256 + threadIdx.x;
    if (i < 256) acc[i] = 0.f;
    if (i < BUCKETS) pos[i] = i * CAP;
}

// ---------------------------------------------------------------------------
// Fused: blocks [0,BKT_BLOCKS) = multisplit bucketing; the rest = linear
// (h = x@W^T + bias via bf16 MFMA, h stored bf16, S1/S2 fused).
// The two phases are data-independent -> they overlap on the device instead
// of serializing on the stream. All 903 blocks co-resident at 4 blk/CU.
// ---------------------------------------------------------------------------
__global__ __launch_bounds__(512, 4) void k_linbucket(
    const float* __restrict__ x, const float* __restrict__ Wmat,
    const float* __restrict__ bias, const float* __restrict__ u_sum,
    ushort* __restrict__ h_bf, float* __restrict__ S1, float* __restrict__ S2,
    const int* __restrict__ src, const float* __restrict__ w,
    const int* __restrict__ dst, int* __restrict__ pos,
    int2* __restrict__ bucketed)
{
    __shared__ int   hist[BUCKETS];
    __shared__ int   cursor[BUCKETS];
    __shared__ float lds_s1[8][32];
    __shared__ float lds_s2[8];

    if (blockIdx.x < BKT_BLOCKS) {
        // ------------------ bucket path (8192 edges per block) ------------
        for (int i = threadIdx.x; i < BUCKETS; i += 512) hist[i] = 0;
        __syncthreads();

        const int E4 = N_EDGES / 4;
        const int tile = blockIdx.x * 2048;
        int4 dd[4];
        #pragma unroll
        for (int i = 0; i < 4; ++i) {
            int e4 = tile + i * 512 + threadIdx.x;
            if (e4 < E4) {
                int4 d = ((const int4*)dst)[e4];
                dd[i] = d;
                atomicAdd(&hist[d.x >> 7], 1);
                atomicAdd(&hist[d.y >> 7], 1);
                atomicAdd(&hist[d.z >> 7], 1);
                atomicAdd(&hist[d.w >> 7], 1);
            } else dd[i].x = -1;
        }
        __syncthreads();
        for (int i = threadIdx.x; i < BUCKETS; i += 512) {
            int hc = hist[i];
            cursor[i] = hc ? atomicAdd(&pos[i], hc) : 0;
        }
        __syncthreads();
        #pragma unroll
        for (int i = 0; i < 4; ++i) {
            int e4 = tile + i * 512 + threadIdx.x;
            if (dd[i].x >= 0) {
                int4   s4 = ((const int4*)src)[e4];
                float4 w4 = ((const float4*)w)[e4];
                int d, p; int2 v;
                d = dd[i].x; p = atomicAdd(&cursor[d >> 7], 1);
                v.x = s4.x | ((d & (NBPB - 1)) << 18); v.y = __float_as_int(w4.x);
                bucketed[p] = v;
                d = dd[i].y; p = atomicAdd(&cursor[d >> 7], 1);
                v.x = s4.y | ((d & (NBPB - 1)) << 18); v.y = __float_as_int(w4.y);
                bucketed[p] = v;
                d = dd[i].z; p = atomicAdd(&cursor[d >> 7], 1);
                v.x = s4.z | ((d & (NBPB - 1)) << 18); v.y = __float_as_int(w4.z);
                bucketed[p] = v;
                d = dd[i].w; p = atomicAdd(&cursor[d >> 7], 1);
                v.x = s4.w | ((d & (NBPB - 1)) << 18); v.y = __float_as_int(w4.w);
                bucketed[p] = v;
            }
        }
        return;
    }

    // ---------------------- linear path (8 waves) -------------------------
    const int lane = threadIdx.x & 63;
    const int wv   = threadIdx.x >> 6;      // 0..7
    const int lr   = lane & 15;
    const int kc   = lane >> 4;

    bf16x8 bfr[8][2];
    #pragma unroll
    for (int ct = 0; ct < 2; ++ct) {
        const float* wp = Wmat + (size_t)(ct * 16 + lr) * FEATS + kc * 8;
        #pragma unroll
        for (int kt = 0; kt < 8; ++kt) {
            f32x4 v0 = *(const f32x4*)(wp + kt * 32);
            f32x4 v1 = *(const f32x4*)(wp + kt * 32 + 4);
            bf16x8 b;
            b[0]=f2bf(v0.x); b[1]=f2bf(v0.y); b[2]=f2bf(v0.z); b[3]=f2bf(v0.w);
            b[4]=f2bf(v1.x); b[5]=f2bf(v1.y); b[6]=f2bf(v1.z); b[7]=f2bf(v1.w);
            bfr[kt][ct] = b;
        }
    }

    const float bias0 = bias[lr], bias1 = bias[16 + lr];
    const float invn = 1.0f / (float)N_NODES;
    float s1_0 = 0.f, s1_1 = 0.f, s2 = 0.f;

    const int bid = blockIdx.x - BKT_BLOCKS;
    const int nlin = gridDim.x - BKT_BLOCKS;
    const int ntiles = N_NODES / 16;
    for (int t = bid * 8 + wv; t < ntiles; t += nlin * 8) {
        const int base = t * 16;
        const float* xp = x + (size_t)(base + lr) * FEATS + kc * 8;
        f32x4 acc0 = {bias0, bias0, bias0, bias0};
        f32x4 acc1 = {bias1, bias1, bias1, bias1};
        #pragma unroll
        for (int kt = 0; kt < 8; ++kt) {
            f32x4 v0 = *(const f32x4*)(xp + kt * 32);
            f32x4 v1 = *(const f32x4*)(xp + kt * 32 + 4);
            bf16x8 a;
            a[0]=f2bf(v0.x); a[1]=f2bf(v0.y); a[2]=f2bf(v0.z); a[3]=f2bf(v0.w);
            a[4]=f2bf(v1.x); a[5]=f2bf(v1.y); a[6]=f2bf(v1.z); a[7]=f2bf(v1.w);
            acc0 = __builtin_amdgcn_mfma_f32_16x16x32_bf16(a, bfr[kt][0], acc0, 0, 0, 0);
            acc1 = __builtin_amdgcn_mfma_f32_16x16x32_bf16(a, bfr[kt][1], acc1, 0, 0, 0);
        }
        #pragma unroll
        for (int i = 0; i < 4; ++i) {
            const int row = base + kc * 4 + i;
            h_bf[(size_t)row * NC + lr]      = (ushort)f2bf(acc0[i]);
            h_bf[(size_t)row * NC + 16 + lr] = (ushort)f2bf(acc1[i]);
            const float um = u_sum[row] * invn;
            float a0 = um * acc0[i], a1 = um * acc1[i];
            s1_0 += a0; s1_1 += a1;
            s2 += a0 * a0 + a1 * a1;
        }
    }

    s1_0 += __shfl_xor(s1_0, 16); s1_0 += __shfl_xor(s1_0, 32);
    s1_1 += __shfl_xor(s1_1, 16); s1_1 += __shfl_xor(s1_1, 32);
    #pragma unroll
    for (int off = 1; off < 64; off <<= 1) s2 += __shfl_xor(s2, off);
    if (lane < 16) { lds_s1[wv][lr] = s1_0; lds_s1[wv][16 + lr] = s1_1; }
    if (lane == 0) lds_s2[wv] = s2;
    __syncthreads();
    if (threadIdx.x < 32) {
        float t8 = 0.f;
        #pragma unroll
        for (int j = 0; j < 8; ++j) t8 += lds_s1[j][threadIdx.x];
        atomAddF(&S1[threadIdx.x], t8);
    }
    if (threadIdx.x == 32) {
        float t8 = 0.f;
        #pragma unroll
        for (int j = 0; j < 8; ++j) t8 += lds_s2[j];
        atomAddF(S2, t8);
    }
}

// ---------------------------------------------------------------------------
// Per-bucket: payloads read ONCE into registers (5/thread), in-LDS counting
// sort to per-node CSR, then per-node register gather with 4-wide unrolled
// independent h-line loads. One 64B line per edge, y written once, colsum
// fused.
// ---------------------------------------------------------------------------
__global__ __launch_bounds__(512) void k_breduce(
    const int2* __restrict__ bucketed, const int* __restrict__ pos,
    const ushort* __restrict__ h_bf,
    float* __restrict__ y, float* __restrict__ colsum)
{
    __shared__ int2  eSort[CAP];         // 20 KB
    __shared__ int   scnt[NBPB];
    __shared__ int   soffs[NBPB];
    __shared__ int   scur[NBPB];
    __shared__ int   ssc[NBPB];
    __shared__ float red[512];

    const int tid = threadIdx.x;
    const int b   = blockIdx.x;
    const int beg = b * CAP;
    const int n   = pos[b] - beg;

    if (tid < NBPB) scnt[tid] = 0;
    __syncthreads();

    // 1) load payloads into registers + count local-dst occupancy
    int2 pr0, pr1, pr2, pr3, pr4;
    int  l0 = -1, l1 = -1, l2 = -1, l3 = -1, l4 = -1;
    if (tid          < n) { pr0 = bucketed[beg + tid];          l0 = (unsigned)pr0.x >> 18; }
    if (tid +  512   < n) { pr1 = bucketed[beg + tid + 512];    l1 = (unsigned)pr1.x >> 18; }
    if (tid + 1024   < n) { pr2 = bucketed[beg + tid + 1024];   l2 = (unsigned)pr2.x >> 18; }
    if (tid + 1536   < n) { pr3 = bucketed[beg + tid + 1536];   l3 = (unsigned)pr3.x >> 18; }
    if (tid + 2048   < n) { pr4 = bucketed[beg + tid + 2048];   l4 = (unsigned)pr4.x >> 18; }
    if (l0 >= 0) atomicAdd(&scnt[l0], 1);
    if (l1 >= 0) atomicAdd(&scnt[l1], 1);
    if (l2 >= 0) atomicAdd(&scnt[l2], 1);
    if (l3 >= 0) atomicAdd(&scnt[l3], 1);
    if (l4 >= 0) atomicAdd(&scnt[l4], 1);
    __syncthreads();

    // 2) exclusive scan over 128 counters
    if (tid < NBPB) ssc[tid] = scnt[tid];
    __syncthreads();
    for (int off = 1; off < NBPB; off <<= 1) {
        int t = 0;
        if (tid < NBPB && tid >= off) t = ssc[tid - off];
        __syncthreads();
        if (tid < NBPB && tid >= off) ssc[tid] += t;
        __syncthreads();
    }
    if (tid < NBPB) {
        int o = ssc[tid] - scnt[tid];
        soffs[tid] = o;
        scur[tid]  = o;
    }
    __syncthreads();

    // 3) scatter register payloads into node-sorted LDS buffer
    if (l0 >= 0) { int q = atomicAdd(&scur[l0], 1); eSort[q] = pr0; }
    if (l1 >= 0) { int q = atomicAdd(&scur[l1], 1); eSort[q] = pr1; }
    if (l2 >= 0) { int q = atomicAdd(&scur[l2], 1); eSort[q] = pr2; }
    if (l3 >= 0) { int q = atomicAdd(&scur[l3], 1); eSort[q] = pr3; }
    if (l4 >= 0) { int q = atomicAdd(&scur[l4], 1); eSort[q] = pr4; }
    __syncthreads();

    // 4) per-node gather, 4-wide independent h-line loads
    const __hip_bfloat16* hb = (const __hip_bfloat16*)h_bf;
    const int c = tid & 31;
    const int g = tid >> 5;              // 0..15
    float scol = 0.f;
    for (int ld = g; ld < NBPB; ld += 16) {
        const int node = b * NBPB + ld;
        if (node >= N_NODES) break;
        int j = soffs[ld];
        const int e = j + scnt[ld];
        float s = 0.f;
        for (; j + 4 <= e; j += 4) {
            int2 p0 = eSort[j], p1 = eSort[j + 1], p2 = eSort[j + 2], p3 = eSort[j + 3];
            float h0 = __bfloat162float(hb[(size_t)(p0.x & 0x3FFFF) * NC + c]);
            float h1 = __bfloat162float(hb[(size_t)(p1.x & 0x3FFFF) * NC + c]);
            float h2 = __bfloat162float(hb[(size_t)(p2.x & 0x3FFFF) * NC + c]);
            float h3 = __bfloat162float(hb[(size_t)(p3.x & 0x3FFFF) * NC + c]);
            s = fmaf(h0, __int_as_float(p0.y), s);
            s = fmaf(h1, __int_as_float(p1.y), s);
            s = fmaf(h2, __int_as_float(p2.y), s);
            s = fmaf(h3, __int_as_float(p3.y), s);
        }
        for (; j < e; ++j) {
            int2 p = eSort[j];
            float hv = __bfloat162float(hb[(size_t)(p.x & 0x3FFFF) * NC + c]);
            s = fmaf(hv, __int_as_float(p.y), s);
        }
        y[(size_t)node * NC + c] = s;
        scol += s;
    }

    red[tid] = scol;
    __syncthreads();
    if (tid < 32) {
        float t = 0.f;
        #pragma unroll
        for (int jj = 0; jj < 16; ++jj) t += red[tid + 32 * jj];
        atomAddF(&colsum[tid], t);
    }
}

// ---------------------------------------------------------------------------
// Fallback path (small workspace): standalone linear + atomic scatter
// ---------------------------------------------------------------------------
__global__ __launch_bounds__(256, 3) void k_linear_fb(
    const float* __restrict__ x, const float* __restrict__ Wmat,
    const float* __restrict__ bias, const float* __restrict__ u_sum,
    ushort* __restrict__ h_bf, float* __restrict__ S1, float* __restrict__ S2)
{
    __shared__ float lds_s1[4][32];
    __shared__ float lds_s2[4];

    const int lane = threadIdx.x & 63;
    const int wv   = threadIdx.x >> 6;
    const int lr   = lane & 15;
    const int kc   = lane >> 4;

    bf16x8 bfr[8][2];
    #pragma unroll
    for (int ct = 0; ct < 2; ++ct) {
        const float* wp = Wmat + (size_t)(ct * 16 + lr) * FEATS + kc * 8;
        #pragma unroll
        for (int kt = 0; kt < 8; ++kt) {
            f32x4 v0 = *(const f32x4*)(wp + kt * 32);
            f32x4 v1 = *(const f32x4*)(wp + kt * 32 + 4);
            bf16x8 b;
            b[0]=f2bf(v0.x); b[1]=f2bf(v0.y); b[2]=f2bf(v0.z); b[3]=f2bf(v0.w);
            b[4]=f2bf(v1.x); b[5]=f2bf(v1.y); b[6]=f2bf(v1.z); b[7]=f2bf(v1.w);
            bfr[kt][ct] = b;
        }
    }

    const float bias0 = bias[lr], bias1 = bias[16 + lr];
    const float invn = 1.0f / (float)N_NODES;
    float s1_0 = 0.f, s1_1 = 0.f, s2 = 0.f;

    const int ntiles = N_NODES / 16;
    for (int t = blockIdx.x * 4 + wv; t < ntiles; t += gridDim.x * 4) {
        const int base = t * 16;
        const float* xp = x + (size_t)(base + lr) * FEATS + kc * 8;
        f32x4 acc0 = {bias0, bias0, bias0, bias0};
        f32x4 acc1 = {bias1, bias1, bias1, bias1};
        #pragma unroll
        for (int kt = 0; kt < 8; ++kt) {
            f32x4 v0 = *(const f32x4*)(xp + kt * 32);
            f32x4 v1 = *(const f32x4*)(xp + kt * 32 + 4);
            bf16x8 a;
            a[0]=f2bf(v0.x); a[1]=f2bf(v0.y); a[2]=f2bf(v0.z); a[3]=f2bf(v0.w);
            a[4]=f2bf(v1.x); a[5]=f2bf(v1.y); a[6]=f2bf(v1.z); a[7]=f2bf(v1.w);
            acc0 = __builtin_amdgcn_mfma_f32_16x16x32_bf16(a, bfr[kt][0], acc0, 0, 0, 0);
            acc1 = __builtin_amdgcn_mfma_f32_16x16x32_bf16(a, bfr[kt][1], acc1, 0, 0, 0);
        }
        #pragma unroll
        for (int i = 0; i < 4; ++i) {
            const int row = base + kc * 4 + i;
            h_bf[(size_t)row * NC + lr]      = (ushort)f2bf(acc0[i]);
            h_bf[(size_t)row * NC + 16 + lr] = (ushort)f2bf(acc1[i]);
            const float um = u_sum[row] * invn;
            float a0 = um * acc0[i], a1 = um * acc1[i];
            s1_0 += a0; s1_1 += a1;
            s2 += a0 * a0 + a1 * a1;
        }
    }

    s1_0 += __shfl_xor(s1_0, 16); s1_0 += __shfl_xor(s1_0, 32);
    s1_1 += __shfl_xor(s1_1, 16); s1_1 += __shfl_xor(s1_1, 32);
    #pragma unroll
    for (int off = 1; off < 64; off <<= 1) s2 += __shfl_xor(s2, off);
    if (lane < 16) { lds_s1[wv][lr] = s1_0; lds_s1[wv][16 + lr] = s1_1; }
    if (lane == 0) lds_s2[wv] = s2;
    __syncthreads();
    if (threadIdx.x < 32) {
        float t4 = lds_s1[0][threadIdx.x] + lds_s1[1][threadIdx.x]
                 + lds_s1[2][threadIdx.x] + lds_s1[3][threadIdx.x];
        atomAddF(&S1[threadIdx.x], t4);
    }
    if (threadIdx.x == 32)
        atomAddF(S2, lds_s2[0] + lds_s2[1] + lds_s2[2] + lds_s2[3]);
}

__global__ __launch_bounds__(256) void k_scatter_atomic(
    const ushort* __restrict__ h_bf, const float* __restrict__ w,
    const int* __restrict__ src, const int* __restrict__ dst,
    float* __restrict__ y)
{
    const __hip_bfloat16* hb = (const __hip_bfloat16*)h_bf;
    const long long total  = (long long)N_EDGES * NC;
    const long long stride = (long long)gridDim.x * 256;
    for (long long i = (long long)blockIdx.x * 256 + threadIdx.x;
         i < total; i += stride) {
        const int e = (int)(i >> 5);
        const int c = (int)(i & 31);
        float hv = __bfloat162float(hb[(size_t)src[e] * NC + c]);
        atomAddF(&y[(size_t)dst[e] * NC + c], hv * w[e]);
    }
}

__global__ __launch_bounds__(256) void k_colsum(
    const float* __restrict__ y, float* __restrict__ colsum)
{
    __shared__ float red[256];
    const long long total  = (long long)N_NODES * NC;
    const long long stride = (long long)gridDim.x * 256;
    float s = 0.f;
    for (long long i = (long long)blockIdx.x * 256 + threadIdx.x;
         i < total; i += stride)
        s += y[i];
    red[threadIdx.x] = s;
    __syncthreads();
    if (threadIdx.x < 32) {
        float t = 0.f;
        #pragma unroll
        for (int j = 0; j < 8; ++j) t += red[threadIdx.x + 32 * j];
        atomAddF(&colsum[threadIdx.x], t);
    }
}

// ---------------------------------------------------------------------------
// loss; acc: [0..31] colsum_y, [32..63] S1, [64] S2
// ---------------------------------------------------------------------------
__global__ void k_final(const float* __restrict__ acc, float* __restrict__ loss_out)
{
    double cross = 0.0, msq = 0.0;
    for (int c = 0; c < NC; ++c) {
        double m = (double)acc[c] / (double)N_NODES;
        cross += m * (double)acc[32 + c];
        msq   += m * m;
    }
    double loss = ((double)acc[64] - 2.0 * cross + (double)N_NODES * msq)
                  / ((double)N_NODES * (double)NC);
    *loss_out = (float)loss;
}

extern "C" void kernel_launch(void* const* d_in, const int* in_sizes, int n_in,
                              void* d_out, int out_size, void* d_ws, size_t ws_size,
                              hipStream_t stream)
{
    const float* x   = (const float*)d_in[0];
    const float* w   = (const float*)d_in[1];
    const float* u   = (const float*)d_in[2];
    const float* Wm  = (const float*)d_in[3];
    const float* Wb  = (const float*)d_in[4];
    const int*   src = (const int*)d_in[5];
    const int*   dst = (const int*)d_in[6];

    float* out = (float*)d_out;                  // y [N*32] then loss [1]

    uint8_t* w8 = (uint8_t*)d_ws;
    float*  acc  = (float*)w8;                   // 256 floats (1 KB)
    int*    pos  = (int*)(w8 + 1024);            // BUCKETS (padded 8 KB)
    ushort* h_bf = (ushort*)(w8 + 1024 + 8192);  // 12.8 MB
    int2*   bucketed = (int2*)(w8 + 1024 + 8192 + (size_t)N_NODES * NC * 2); // 32 MB

    const size_t need = 1024 + 8192 + (size_t)N_NODES * NC * 2
                      + (size_t)BUCKETS * CAP * 8;

    if (ws_size >= need) {
        k_init     <<<8, 256, 0, stream>>>(acc, pos);
        k_linbucket<<<BKT_BLOCKS + LIN_BLOCKS, 512, 0, stream>>>(
            x, Wm, Wb, u, h_bf, acc + 32, acc + 64, src, w, dst, pos, bucketed);
        k_breduce  <<<BUCKETS, 512, 0, stream>>>(bucketed, pos, h_bf, out, acc);
    } else {
        k_init<<<8, 256, 0, stream>>>(acc, pos);
        hipMemsetAsync(d_out, 0, (size_t)out_size * sizeof(float), stream);
        k_linear_fb     <<<1024, 256, 0, stream>>>(x, Wm, Wb, u, h_bf, acc + 32, acc + 64);
        k_scatter_atomic<<<8192, 256, 0, stream>>>(h_bf, w, src, dst, out);
        k_colsum        <<<2048, 256, 0, stream>>>(out, acc);
    }

    k_final<<<1, 1, 0, stream>>>(acc, out + (size_t)N_NODES * NC);
}